// Round 1
// 78.106 us; speedup vs baseline: 1.0571x; 1.0571x over previous
//
#include <hip/hip_runtime.h>

// InstanceSegmentationLoss — 2-dispatch form (R3-proven structure).
//
// Reference == 33x33 joint histogram J[p][t] over 4.19M pixels + O(33^2) IoU.
//
// Timed-region model (R0 of this session): ~44 us is the harness's 256 MiB
// d_ws zero-fill (fillBufferAligned @6.1 TB/s, visible in rocprof, not ours
// to remove) + ~15-20 us harness memsets/launch overhead + ~16-20 us of our
// two kernels. This round shrinks the kernel slice:
//   - NREP 32 -> 8: finalize's LLC reduce loads 34848 -> 8712, re-zero
//     147 KB -> 36 KB (it is single-block latency-bound, so this is the
//     biggest controllable line item).
//   - 64-bit agent-scope zero stores (halve store count).
//   - __syncthreads() between reduce and re-zero (the old code could zero a
//     replica word before another thread had loaded it — latent race).
//   - bin path: ids are exact small ints, so idx = med3(p*33+t, 0, 1088)
//     (1 fma + 1 med3 + 1 cvt per pixel vs two cvt+clamp chains) — still
//     clamped, so poisoned inputs can't scribble outside the LDS histogram.
//
// Cross-dispatch data moves via agent-scope atomics executed at the LLC
// (bypassing non-coherent per-XCD L2s); dispatch boundary gives ordering.
// g_part is .bss (zero at load); finalize re-zeroes it each call -> the
// zero-at-entry invariant holds on every graph replay. d_ws unused.

#define NIDS    33               // ids 0..32 (0 = background)
#define HSIZE   (NIDS * NIDS)    // 1089
#define RSTRIDE 1152             // 1089 padded to 64B-line multiple (u32 units)
#define NREP    8                // histogram replicas at the LLC

__device__ __align__(16) unsigned g_part[NREP * RSTRIDE];  // zero-init, self-cleaned

__device__ __forceinline__ void bin1(unsigned* sh, float p, float t) {
    // p,t are exact integers in [0,32] (randint -> float). p*33+t <= 1088 is
    // exact in f32. Single clamp keeps memory-safety under poisoned inputs
    // (fmax(NaN,0)=0 per IEEE, so even NaN lands in-bounds).
    float f = fminf(fmaxf(p * 33.0f + t, 0.0f), 1088.0f);  // v_med3_f32
    atomicAdd(&sh[(unsigned)f], 1u);
}

__device__ __forceinline__ void bin4(unsigned* sh, float4 p, float4 t) {
    bin1(sh, p.x, t.x);
    bin1(sh, p.y, t.y);
    bin1(sh, p.z, t.z);
    bin1(sh, p.w, t.w);
}

__global__ void __launch_bounds__(1024)
hist_kernel(const float4* __restrict__ pred,
            const float4* __restrict__ tmask, int n4) {
    __shared__ unsigned sh[HSIZE];

    const int tid = threadIdx.x;
    for (int i = tid; i < HSIZE; i += blockDim.x) sh[i] = 0u;
    __syncthreads();

    // per-block LDS histogram, 4-way unrolled float4 loads (8 loads in flight)
    const int tot = gridDim.x * blockDim.x;   // 262144 -> exactly 4 float4/thread
    int i = blockIdx.x * blockDim.x + tid;
    for (; i + 3 * tot < n4; i += 4 * tot) {
        float4 p0 = pred[i],           t0 = tmask[i];
        float4 p1 = pred[i + tot],     t1 = tmask[i + tot];
        float4 p2 = pred[i + 2 * tot], t2 = tmask[i + 2 * tot];
        float4 p3 = pred[i + 3 * tot], t3 = tmask[i + 3 * tot];
        bin4(sh, p0, t0);
        bin4(sh, p1, t1);
        bin4(sh, p2, t2);
        bin4(sh, p3, t3);
    }
    for (; i < n4; i += tot) bin4(sh, pred[i], tmask[i]);
    __syncthreads();

    // flush to replica (blockIdx & 7): agent-scope atomics at the LLC.
    // No fence — the dispatch boundary orders this vs finalize_kernel.
    unsigned* rep = &g_part[(blockIdx.x & (NREP - 1)) * RSTRIDE];
    for (int j = tid; j < HSIZE; j += blockDim.x) {
        unsigned v = sh[j];
        if (v) atomicAdd(&rep[j], v);
    }
}

__global__ void __launch_bounds__(1024)
finalize_kernel(float* __restrict__ out) {
    __shared__ float shf[HSIZE];
    __shared__ float rowsum[NIDS], colsum[NIDS];
    __shared__ float maxv[32];

    const int tid = threadIdx.x;
    // reduce 8 replicas (agent-scope loads at LLC — always coherent)
    for (int j = tid; j < HSIZE; j += blockDim.x) {
        unsigned s = 0u;
        #pragma unroll
        for (int r = 0; r < NREP; ++r)
            s += __hip_atomic_load(&g_part[r * RSTRIDE + j], __ATOMIC_RELAXED,
                                   __HIP_MEMORY_SCOPE_AGENT);
        shf[j] = (float)s;
    }
    // all loads done before anyone zeroes (reduce/zero cover different j->word
    // mappings across threads — without this barrier a fast wave could zero a
    // word a slow wave hasn't loaded yet)
    __syncthreads();
    // re-zero for next call: 64-bit agent-scope stores -> land at LLC, next
    // call's flush atomics see them
    unsigned long long* gz = (unsigned long long*)g_part;
    for (int j = tid; j < (NREP * RSTRIDE) / 2; j += blockDim.x)
        __hip_atomic_store(&gz[j], 0ull, __ATOMIC_RELAXED,
                           __HIP_MEMORY_SCOPE_AGENT);
    __syncthreads();

    if (tid < NIDS) {
        float rs = 0.f, cs = 0.f;
        for (int j = 0; j < NIDS; ++j) {
            rs += shf[tid * NIDS + j];
            cs += shf[j * NIDS + tid];
        }
        rowsum[tid] = rs;
        colsum[tid] = cs;
    }
    __syncthreads();

    if (tid < 32) {
        const int n = tid + 1;  // pred instance 1..32
        float best = 0.f;
        const float rs = rowsum[n];
        for (int m = 1; m < NIDS; ++m) {
            float inter = shf[n * NIDS + m];
            float uni   = rs + colsum[m] - inter;
            float iou   = (uni > 0.f) ? (inter / uni) : 0.f;
            best = fmaxf(best, iou);
        }
        maxv[tid] = best;
    }
    __syncthreads();

    if (tid == 0) {
        double sp = 0.0, st = 0.0;
        for (int k = 1; k < NIDS; ++k) {
            sp += (double)k * (double)rowsum[k];
            st += (double)k * (double)colsum[k];
        }
        float loss = 0.f;
        for (int k = 0; k < 32; ++k) loss += 1.0f - maxv[k];
        out[0] = loss + (float)((sp + st) * 1e-12);
    }
}

extern "C" void kernel_launch(void* const* d_in, const int* in_sizes, int n_in,
                              void* d_out, int out_size, void* d_ws, size_t ws_size,
                              hipStream_t stream) {
    const float* pred  = (const float*)d_in[0];
    const float* tmask = (const float*)d_in[1];
    float* out = (float*)d_out;

    const int n  = in_sizes[0];  // 2048*2048 = 4194304
    const int n4 = n / 4;

    // 256 blocks x 1024 threads: 1 block/CU, 16 waves/CU; exactly 4 float4
    // pairs per thread; flush = 279K atomics spread over 8 replicas.
    hist_kernel<<<256, 1024, 0, stream>>>((const float4*)pred,
                                          (const float4*)tmask, n4);
    finalize_kernel<<<1, 1024, 0, stream>>>(out);
}